// Round 1
// baseline (9169.344 us; speedup 1.0000x reference)
//
#include <hip/hip_runtime.h>
#include <math.h>

#define DMODEL 512
#define NHEAD  8
#define DHEAD  64
#define SEQ    512
#define BATCH  4
#define NLAYER 6
#define FFDIM  2048
#define VOCAB  32000

// ---------------------------------------------------------------------------
// Embedding * sqrt(D) + sinusoidal positional encoding
// grid: B*S blocks, 256 threads
// ---------------------------------------------------------------------------
__global__ void embed_kernel(const int* __restrict__ tokens,
                             const float* __restrict__ emb,
                             float* __restrict__ x) {
    int idx = blockIdx.x;              // b*S + s
    int s   = idx & (SEQ - 1);
    int tok = tokens[idx];
    const float scale = 22.627416997969522f;  // sqrt(512)
    for (int d = threadIdx.x; d < DMODEL; d += blockDim.x) {
        float i2  = (float)((d >> 1) << 1) / (float)DMODEL;
        float inv = powf(10000.0f, -i2);
        float em  = (float)s * inv;
        float pe  = ((d & 1) == 0) ? sinf(em) : cosf(em);
        x[(size_t)idx * DMODEL + d] = emb[(size_t)tok * DMODEL + d] * scale + pe;
    }
}

// ---------------------------------------------------------------------------
// C[m,n] = sum_k A[m,k] * W[n,k] + bias[n]   (optionally ReLU)
// A: [M,K] row-major, W: [N,K] row-major (torch-style [out,in]).
// 64x64 tile, TK=16, 256 threads, 4x4 micro-tile per thread.
// Requires M%64==0, N%64==0, K%16==0 (true for all shapes here).
// ---------------------------------------------------------------------------
#define TM 64
#define TN 64
#define TK 16
__global__ __launch_bounds__(256) void gemm_bias(
        const float* __restrict__ A, const float* __restrict__ W,
        const float* __restrict__ bias, float* __restrict__ C,
        int M, int N, int K, int relu) {
    __shared__ float As[TM][TK + 1];
    __shared__ float Bs[TN][TK + 1];
    int bm  = blockIdx.y * TM;
    int bn  = blockIdx.x * TN;
    int tid = threadIdx.x;
    int tx  = tid & 15;        // 0..15 -> N micro
    int ty  = tid >> 4;        // 0..15 -> M micro
    float acc[4][4] = {};

    for (int k0 = 0; k0 < K; k0 += TK) {
#pragma unroll
        for (int i = 0; i < 4; i++) {
            int r = (tid >> 4) + i * 16;          // 0..63
            int c = tid & 15;                     // 0..15
            As[r][c] = A[(size_t)(bm + r) * K + k0 + c];
            Bs[r][c] = W[(size_t)(bn + r) * K + k0 + c];
        }
        __syncthreads();
#pragma unroll
        for (int kk = 0; kk < TK; kk++) {
            float a[4], b[4];
#pragma unroll
            for (int i = 0; i < 4; i++) a[i] = As[ty * 4 + i][kk];
#pragma unroll
            for (int j = 0; j < 4; j++) b[j] = Bs[tx * 4 + j][kk];
#pragma unroll
            for (int i = 0; i < 4; i++)
#pragma unroll
                for (int j = 0; j < 4; j++) acc[i][j] += a[i] * b[j];
        }
        __syncthreads();
    }

#pragma unroll
    for (int i = 0; i < 4; i++) {
        int row = bm + ty * 4 + i;
#pragma unroll
        for (int j = 0; j < 4; j++) {
            int col = bn + tx * 4 + j;
            float v = acc[i][j] + bias[col];
            if (relu) v = fmaxf(v, 0.0f);
            C[(size_t)row * N + col] = v;
        }
    }
}

// ---------------------------------------------------------------------------
// Row-wise attention: one block per (b, h, q-row). S=512, dh=64.
// causal=1: mask = max(tokens[b,k]==0, k>q); causal=0: mask = en_pad[b,k].
// ---------------------------------------------------------------------------
__global__ __launch_bounds__(256) void attn_kernel(
        const float* __restrict__ Q, const float* __restrict__ K,
        const float* __restrict__ Vv, const int* __restrict__ tokens,
        const float* __restrict__ en_pad, float* __restrict__ O, int causal) {
    int qi = blockIdx.x;
    int h  = blockIdx.y;
    int b  = blockIdx.z;
    int t  = threadIdx.x;

    __shared__ float qs[DHEAD];
    __shared__ float sc[SEQ];
    __shared__ float red[256];
    __shared__ float ored[4][DHEAD];

    const float* qrow = Q + ((size_t)b * SEQ + qi) * DMODEL + h * DHEAD;
    if (t < DHEAD) qs[t] = qrow[t];
    __syncthreads();

    // scores
    for (int j = t; j < SEQ; j += 256) {
        const float* krow = K + ((size_t)b * SEQ + j) * DMODEL + h * DHEAD;
        float acc = 0.0f;
#pragma unroll
        for (int d = 0; d < DHEAD; d++) acc += qs[d] * krow[d];
        float m;
        if (causal) {
            float pad = (tokens[b * SEQ + j] == 0) ? 1.0f : 0.0f;
            float tri = (j > qi) ? 1.0f : 0.0f;
            m = fmaxf(pad, tri);
        } else {
            m = en_pad[b * SEQ + j];
        }
        sc[j] = acc * 0.125f - m * 1.0e6f;
    }
    __syncthreads();

    // max
    float lm = -INFINITY;
    for (int j = t; j < SEQ; j += 256) lm = fmaxf(lm, sc[j]);
    red[t] = lm;
    __syncthreads();
    for (int off = 128; off > 0; off >>= 1) {
        if (t < off) red[t] = fmaxf(red[t], red[t + off]);
        __syncthreads();
    }
    float mx = red[0];
    __syncthreads();

    // exp + sum
    float ls = 0.0f;
    for (int j = t; j < SEQ; j += 256) {
        float e = expf(sc[j] - mx);
        sc[j] = e;
        ls += e;
    }
    red[t] = ls;
    __syncthreads();
    for (int off = 128; off > 0; off >>= 1) {
        if (t < off) red[t] += red[t + off];
        __syncthreads();
    }
    float ssum = red[0];
    __syncthreads();

    // output: thread t handles dim t&63, key-chunk t>>6 (4 chunks of 128)
    int d = t & 63;
    int chunk = t >> 6;
    float acc = 0.0f;
    const float* vbase = Vv + (size_t)b * SEQ * DMODEL + h * DHEAD + d;
    for (int j = chunk * 128; j < (chunk + 1) * 128; j++)
        acc += sc[j] * vbase[(size_t)j * DMODEL];
    ored[chunk][d] = acc;
    __syncthreads();
    if (t < DHEAD) {
        float o = (ored[0][t] + ored[1][t] + ored[2][t] + ored[3][t]) / ssum;
        O[((size_t)b * SEQ + qi) * DMODEL + h * DHEAD + t] = o;
    }
}

// ---------------------------------------------------------------------------
// out = LayerNorm(x + y) * g + b, row length 512, one block per row
// ---------------------------------------------------------------------------
__global__ __launch_bounds__(256) void ln_res_kernel(
        const float* __restrict__ x, const float* __restrict__ y,
        const float* __restrict__ g, const float* __restrict__ b,
        float* __restrict__ out) {
    int row = blockIdx.x;
    int t   = threadIdx.x;
    __shared__ float red[256];
    size_t base = (size_t)row * DMODEL;
    float v0 = x[base + t] + y[base + t];
    float v1 = x[base + t + 256] + y[base + t + 256];

    red[t] = v0 + v1;
    __syncthreads();
    for (int off = 128; off > 0; off >>= 1) {
        if (t < off) red[t] += red[t + off];
        __syncthreads();
    }
    float mu = red[0] * (1.0f / 512.0f);
    __syncthreads();

    float d0 = v0 - mu, d1 = v1 - mu;
    red[t] = d0 * d0 + d1 * d1;
    __syncthreads();
    for (int off = 128; off > 0; off >>= 1) {
        if (t < off) red[t] += red[t + off];
        __syncthreads();
    }
    float inv = rsqrtf(red[0] * (1.0f / 512.0f) + 1e-6f);
    out[base + t]       = d0 * inv * g[t]       + b[t];
    out[base + t + 256] = d1 * inv * g[t + 256] + b[t + 256];
}

// ---------------------------------------------------------------------------
extern "C" void kernel_launch(void* const* d_in, const int* in_sizes, int n_in,
                              void* d_out, int out_size, void* d_ws, size_t ws_size,
                              hipStream_t stream) {
    const int*   tokens = (const int*)  d_in[0];
    const float* en_out = (const float*)d_in[1];
    const float* en_pad = (const float*)d_in[2];
    const float* emb    = (const float*)d_in[3];
    const float* sa_w   = (const float*)d_in[4];
    const float* sa_b   = (const float*)d_in[5];
    const float* ca_w   = (const float*)d_in[6];
    const float* ca_b   = (const float*)d_in[7];
    const float* ff_w1  = (const float*)d_in[8];
    const float* ff_b1  = (const float*)d_in[9];
    const float* ff_w2  = (const float*)d_in[10];
    const float* ff_b2  = (const float*)d_in[11];
    const float* ln_g   = (const float*)d_in[12];
    const float* ln_b   = (const float*)d_in[13];
    const float* out_w  = (const float*)d_in[14];
    const float* out_b  = (const float*)d_in[15];
    float* logits = (float*)d_out;

    const int BS = BATCH * SEQ;            // 2048
    const size_t NTOK = (size_t)BS * DMODEL;  // 1 << 20

    // workspace layout (floats): 44 MB total
    float* ws   = (float*)d_ws;
    float* buf0 = ws;                 // state A
    float* buf1 = ws + NTOK;          // state B
    float* q    = ws + 2 * NTOK;
    float* k    = ws + 3 * NTOK;
    float* v    = ws + 4 * NTOK;
    float* att  = ws + 5 * NTOK;
    float* proj = ws + 6 * NTOK;
    float* ffb  = ws + 7 * NTOK;      // B*S*FF = 4M floats

    dim3 gemm_dd(DMODEL / TN, BS / TM);     // [2048,512]x[512,512]
    dim3 gemm_df(FFDIM / TN, BS / TM);      // [2048,512]x[512,2048]
    dim3 gemm_fd(DMODEL / TN, BS / TM);     // [2048,2048]x[2048,512]
    dim3 gemm_v(VOCAB / TN, BS / TM);       // [2048,512]x[512,32000]
    dim3 attn_grid(SEQ, NHEAD, BATCH);

    embed_kernel<<<BS, 256, 0, stream>>>(tokens, emb, buf0);

    float* cur = buf0;
    float* oth = buf1;
    for (int l = 0; l < NLAYER; l++) {
        const float* sw = sa_w + (size_t)l * 4 * DMODEL * DMODEL;
        const float* sb = sa_b + (size_t)l * 4 * DMODEL;
        const float* cw = ca_w + (size_t)l * 4 * DMODEL * DMODEL;
        const float* cb = ca_b + (size_t)l * 4 * DMODEL;
        const float* lg = ln_g + (size_t)l * 3 * DMODEL;
        const float* lb = ln_b + (size_t)l * 3 * DMODEL;

        // ---- self-attention ----
        gemm_bias<<<gemm_dd, 256, 0, stream>>>(cur, sw + 0 * DMODEL * DMODEL, sb + 0 * DMODEL, q, BS, DMODEL, DMODEL, 0);
        gemm_bias<<<gemm_dd, 256, 0, stream>>>(cur, sw + 1 * DMODEL * DMODEL, sb + 1 * DMODEL, k, BS, DMODEL, DMODEL, 0);
        gemm_bias<<<gemm_dd, 256, 0, stream>>>(cur, sw + 2 * DMODEL * DMODEL, sb + 2 * DMODEL, v, BS, DMODEL, DMODEL, 0);
        attn_kernel<<<attn_grid, 256, 0, stream>>>(q, k, v, tokens, nullptr, att, 1);
        gemm_bias<<<gemm_dd, 256, 0, stream>>>(att, sw + 3 * DMODEL * DMODEL, sb + 3 * DMODEL, proj, BS, DMODEL, DMODEL, 0);
        ln_res_kernel<<<BS, 256, 0, stream>>>(cur, proj, lg + 0 * DMODEL, lb + 0 * DMODEL, oth);  // h -> oth

        // ---- cross-attention ----
        gemm_bias<<<gemm_dd, 256, 0, stream>>>(oth,    cw + 0 * DMODEL * DMODEL, cb + 0 * DMODEL, q, BS, DMODEL, DMODEL, 0);
        gemm_bias<<<gemm_dd, 256, 0, stream>>>(en_out, cw + 1 * DMODEL * DMODEL, cb + 1 * DMODEL, k, BS, DMODEL, DMODEL, 0);
        gemm_bias<<<gemm_dd, 256, 0, stream>>>(en_out, cw + 2 * DMODEL * DMODEL, cb + 2 * DMODEL, v, BS, DMODEL, DMODEL, 0);
        attn_kernel<<<attn_grid, 256, 0, stream>>>(q, k, v, tokens, en_pad, att, 0);
        gemm_bias<<<gemm_dd, 256, 0, stream>>>(att, cw + 3 * DMODEL * DMODEL, cb + 3 * DMODEL, proj, BS, DMODEL, DMODEL, 0);
        ln_res_kernel<<<BS, 256, 0, stream>>>(oth, proj, lg + 1 * DMODEL, lb + 1 * DMODEL, cur);  // a -> cur

        // ---- feed-forward ----
        gemm_bias<<<gemm_df, 256, 0, stream>>>(cur, ff_w1 + (size_t)l * FFDIM * DMODEL, ff_b1 + (size_t)l * FFDIM, ffb, BS, FFDIM, DMODEL, 1);
        gemm_bias<<<gemm_fd, 256, 0, stream>>>(ffb, ff_w2 + (size_t)l * DMODEL * FFDIM, ff_b2 + (size_t)l * DMODEL, proj, BS, DMODEL, FFDIM, 0);
        ln_res_kernel<<<BS, 256, 0, stream>>>(cur, proj, lg + 2 * DMODEL, lb + 2 * DMODEL, oth);  // x -> oth

        float* t2 = cur; cur = oth; oth = t2;
    }

    // final vocab projection
    gemm_bias<<<gemm_v, 256, 0, stream>>>(cur, out_w, out_b, logits, BS, VOCAB, DMODEL, 0);
}